// Round 12
// baseline (369.048 us; speedup 1.0000x reference)
//
#include <hip/hip_runtime.h>

#define N_NODES 20000
#define N_EDGES 320000
#define HD 128
#define FIN 162      // 24 + 10 + 128
#define KE 260       // 2*H + ETN
#define KPAD 288     // edge K padded: 9 chunks of 32
#define KOP 192      // encode K padded: 6 chunks of 32
#define WSTR 296     // edge W LDS row stride (u16): 592B
#define OSTR 200     // encode W LDS row stride (u16)
#define GSTR 136     // geo W LDS row stride (u16)
#define TSTR 136     // transpose row stride (u16): 128 ch + 8 pad

typedef unsigned short u16;
typedef __attribute__((ext_vector_type(8))) short bf16x8;
typedef __attribute__((ext_vector_type(4))) float f32x4;

__device__ __forceinline__ float leaky(float x){ return x > 0.f ? x : 0.01f*x; }
__device__ __forceinline__ unsigned fmap(float f){
    unsigned u = __float_as_uint(f);
    return (u & 0x80000000u) ? ~u : (u | 0x80000000u);
}
__device__ __forceinline__ float funmap(unsigned u){
    return __uint_as_float((u & 0x80000000u) ? (u & 0x7fffffffu) : ~u);
}
__device__ __forceinline__ unsigned umax_(unsigned a, unsigned b){ return a > b ? a : b; }
__device__ __forceinline__ u16 f2bf(float x){
    unsigned b = __float_as_uint(x);
    return (u16)((b + 0x7fffu + ((b >> 16) & 1u)) >> 16);
}
__device__ __forceinline__ float bf2f(u16 u){
    return __uint_as_float(((unsigned)u) << 16);
}

// ---------------------------------------------------------------------------
// prep: fully-vectorized bf16 conversions + from-histogram
// ---------------------------------------------------------------------------
#define PB_W 16
#define PB_F 960
#define PB_G 640
#define PB_H 320
#define PREP_GRID (PB_W + PB_F + PB_G + PB_H)

__global__ __launch_bounds__(256) void prep(
    const float* __restrict__ edge_w, u16* __restrict__ Wb,
    const float* __restrict__ op_w,   u16* __restrict__ Wop,
    const float* __restrict__ geo_w,  u16* __restrict__ Wgeo,
    const float* __restrict__ skip_w, u16* __restrict__ Wskip,
    const float* __restrict__ feats,  u16* __restrict__ featsb,
    const float* __restrict__ geof,   u16* __restrict__ geob,
    const int* __restrict__ eidx, int* __restrict__ count)
{
    const int b = blockIdx.x, t = threadIdx.x;
    if (b < PB_W) {
        for (int idx = b * 256 + t; idx < 16384; idx += PB_W * 256) {
            union { u16 us[8]; uint4 v; } pk;
            if (idx < 9216) {
                int layer = idx / 4608, rem = idx - layer * 4608;
                int h = rem / 36, j = rem - h * 36;
                const float* src = edge_w + (size_t)layer * 128 * KE + h * KE;
                #pragma unroll
                for (int kk = 0; kk < 8; ++kk) {
                    int k = j * 8 + kk;
                    pk.us[kk] = (k < KE) ? f2bf(src[k]) : (u16)0;
                }
                ((uint4*)Wb)[(size_t)layer * 128 * 36 + h * 36 + j] = pk.v;
            } else if (idx < 12288) {
                int rem = idx - 9216;
                int h = rem / 24, j = rem - h * 24;
                const float* src = op_w + h * FIN;
                #pragma unroll
                for (int kk = 0; kk < 8; ++kk) {
                    int k = j * 8 + kk;
                    pk.us[kk] = (k < FIN) ? f2bf(src[k]) : (u16)0;
                }
                ((uint4*)Wop)[h * 24 + j] = pk.v;
            } else {
                int rem = idx - 12288;
                int which = rem >> 11;
                int r2 = rem & 2047;
                const float4* src = (const float4*)((which ? skip_w : geo_w)) + r2 * 2;
                float4 a = src[0], c = src[1];
                pk.us[0]=f2bf(a.x); pk.us[1]=f2bf(a.y); pk.us[2]=f2bf(a.z); pk.us[3]=f2bf(a.w);
                pk.us[4]=f2bf(c.x); pk.us[5]=f2bf(c.y); pk.us[6]=f2bf(c.z); pk.us[7]=f2bf(c.w);
                ((uint4*)(which ? Wskip : Wgeo))[r2] = pk.v;
            }
        }
    } else if (b < PB_W + PB_F) {
        for (int f = (b - PB_W) * 256 + t; f < N_NODES * 24; f += PB_F * 256) {
            int n = f / 24, j = f - n * 24;
            union { u16 us[8]; uint4 v; } pk;
            if (j < 20) {
                const float2* src = (const float2*)(feats + (size_t)n * FIN + j * 8);
                float2 p0 = src[0], p1 = src[1], p2 = src[2], p3 = src[3];
                pk.us[0]=f2bf(p0.x); pk.us[1]=f2bf(p0.y); pk.us[2]=f2bf(p1.x); pk.us[3]=f2bf(p1.y);
                pk.us[4]=f2bf(p2.x); pk.us[5]=f2bf(p2.y); pk.us[6]=f2bf(p3.x); pk.us[7]=f2bf(p3.y);
            } else if (j == 20) {
                float2 p = *(const float2*)(feats + (size_t)n * FIN + 160);
                pk.us[0]=f2bf(p.x); pk.us[1]=f2bf(p.y);
                pk.us[2]=pk.us[3]=pk.us[4]=pk.us[5]=pk.us[6]=pk.us[7]=0;
            } else {
                #pragma unroll
                for (int kk = 0; kk < 8; ++kk) pk.us[kk] = 0;
            }
            ((uint4*)featsb)[(size_t)n * 24 + j] = pk.v;
        }
    } else if (b < PB_W + PB_F + PB_G) {
        for (int g = (b - PB_W - PB_F) * 256 + t; g < N_NODES * 16; g += PB_G * 256) {
            const float4* s = (const float4*)geof + (size_t)g * 2;
            float4 a = s[0], c = s[1];
            union { u16 us[8]; uint4 v; } pk;
            pk.us[0]=f2bf(a.x); pk.us[1]=f2bf(a.y); pk.us[2]=f2bf(a.z); pk.us[3]=f2bf(a.w);
            pk.us[4]=f2bf(c.x); pk.us[5]=f2bf(c.y); pk.us[6]=f2bf(c.z); pk.us[7]=f2bf(c.w);
            ((uint4*)geob)[g] = pk.v;
        }
    } else {
        for (int e = (b - PB_W - PB_F - PB_G) * 256 + t; e < N_EDGES; e += PB_H * 256)
            atomicAdd(&count[eidx[2 * e]], 1);
    }
}

// ---------------------------------------------------------------------------
__global__ __launch_bounds__(1024) void scan_offsets(
    const int* __restrict__ count, int* __restrict__ offset)
{
    __shared__ int part[1024];
    const int t = threadIdx.x;
    const int lo = t * 20;
    const int hi = min(lo + 20, N_NODES);
    int s = 0;
    for (int n = lo; n < hi; ++n) s += count[n];
    part[t] = s;
    __syncthreads();
    for (int d = 1; d < 1024; d <<= 1) {
        int v = (t >= d) ? part[t - d] : 0;
        __syncthreads();
        part[t] += v;
        __syncthreads();
    }
    int run = (t > 0) ? part[t - 1] : 0;
    for (int n = lo; n < hi; ++n) { offset[n] = run; run += count[n]; }
}

// ---------------------------------------------------------------------------
// mid: blocks [0,1250) fill_perm | [1250,1721) node MFMA
// ---------------------------------------------------------------------------
__global__ __launch_bounds__(256) void mid(
    const int* __restrict__ eidx, const float* __restrict__ ef,
    const int* __restrict__ offset, int* __restrict__ cursor,
    int* __restrict__ from_p, int* __restrict__ to_p, uint2* __restrict__ efb_p,
    const u16* __restrict__ featsb, const u16* __restrict__ geob,
    const float* __restrict__ exists,
    const u16* __restrict__ Wop, const float* __restrict__ op_b,
    const u16* __restrict__ Wgeo, const float* __restrict__ geo_b,
    const u16* __restrict__ Wskip, const float* __restrict__ skip_b,
    u16* __restrict__ cf_a,
    unsigned* __restrict__ ipf0_m, unsigned* __restrict__ pg_m,
    unsigned* __restrict__ sg_m)
{
    __shared__ __align__(16) u16 smem[128 * OSTR];   // 51200 B
    __shared__ float ex_s[128];
    __shared__ unsigned colmax_s[128];

    const int blk = blockIdx.x, t = threadIdx.x;
    if (blk < 1250) {
        int e = blk * 256 + t;
        int2 p = ((const int2*)eidx)[e];
        int pos = offset[p.x] + atomicAdd(&cursor[p.x], 1);
        from_p[pos] = p.x; to_p[pos] = p.y;
        float4 e4 = ((const float4*)ef)[e];
        efb_p[pos] = make_uint2(
            (unsigned)f2bf(e4.x) | ((unsigned)f2bf(e4.y) << 16),
            (unsigned)f2bf(e4.z) | ((unsigned)f2bf(e4.w) << 16));
        return;
    }
    const int b = blk - 1250;
    const int mode = (b < 157) ? 0 : (b < 314) ? 1 : 2;
    const int bx = b - (mode == 0 ? 0 : mode == 1 ? 157 : 314);
    const int base = bx * 128;
    const int wave = t >> 6, l = t & 63;
    const int quad = l >> 4, lc = l & 15;
    const int R0 = (wave >> 1) * 64;
    const int C0 = (wave & 1) * 64;

    const u16* W = (mode == 0) ? Wop : (mode == 1) ? Wgeo : Wskip;
    const float* bias = (mode == 0) ? op_b : (mode == 1) ? geo_b : skip_b;
    unsigned* accout = (mode == 0) ? ipf0_m : (mode == 1) ? pg_m : sg_m;
    const int KW = (mode == 0) ? KOP : HD;
    const int SW = (mode == 0) ? OSTR : GSTR;
    const int NCH = (mode == 0) ? 6 : 4;
    const u16* A = (mode == 0) ? featsb : geob;

    {
        const int r = t >> 1, half = t & 1;
        const int nu4 = KW / 16;
        const uint4* src = (const uint4*)(W + (size_t)r * KW) + half * nu4;
        uint4* dst = (uint4*)(smem + r * SW) + half * nu4;
        for (int i = 0; i < nu4; ++i) dst[i] = src[i];
    }
    if (t < 128) {
        int n = base + t; if (n >= N_NODES) n = N_NODES - 1;
        ex_s[t] = exists[n];
        colmax_s[t] = 0u;
    }
    __syncthreads();

    f32x4 acc[4][4];
    #pragma unroll
    for (int i = 0; i < 4; ++i)
        #pragma unroll
        for (int j = 0; j < 4; ++j) acc[i][j] = (f32x4){0.f, 0.f, 0.f, 0.f};

    int nd[4];
    #pragma unroll
    for (int ti = 0; ti < 4; ++ti) {
        int n = base + R0 + ti * 16 + lc;
        nd[ti] = (n < N_NODES) ? n : N_NODES - 1;
    }

    for (int c = 0; c < NCH; ++c) {
        bf16x8 af[4], bfr[4];
        #pragma unroll
        for (int ti = 0; ti < 4; ++ti)
            af[ti] = *(const bf16x8*)(A + (size_t)nd[ti] * KW + c * 32 + quad * 8);
        #pragma unroll
        for (int tj = 0; tj < 4; ++tj)
            bfr[tj] = *(const bf16x8*)(smem + (C0 + tj * 16 + lc) * SW + c * 32 + quad * 8);
        #pragma unroll
        for (int ti = 0; ti < 4; ++ti)
            #pragma unroll
            for (int tj = 0; tj < 4; ++tj)
                acc[ti][tj] = __builtin_amdgcn_mfma_f32_16x16x32_bf16(
                    af[ti], bfr[tj], acc[ti][tj], 0, 0, 0);
    }

    #pragma unroll
    for (int tj = 0; tj < 4; ++tj) {
        const int col = C0 + tj * 16 + lc;
        const float bc = bias[col];
        unsigned mx = 0u;
        #pragma unroll
        for (int ti = 0; ti < 4; ++ti) {
            #pragma unroll
            for (int r = 0; r < 4; ++r) {
                int row = R0 + ti * 16 + quad * 4 + r;
                float x = (acc[ti][tj][r] + bc) * ex_s[row];
                acc[ti][tj][r] = x;
                mx = umax_(mx, fmap(x));
            }
        }
        atomicMax(&colmax_s[col], mx);
    }
    __syncthreads();
    if (t < 128) atomicMax(&accout[t], colmax_s[t]);

    if (mode == 0) {
        #pragma unroll
        for (int ti = 0; ti < 4; ++ti)
            #pragma unroll
            for (int tj = 0; tj < 4; ++tj) {
                const int col = C0 + tj * 16 + lc;
                #pragma unroll
                for (int r = 0; r < 4; ++r)
                    smem[(R0 + ti * 16 + quad * 4 + r) * TSTR + col] = f2bf(acc[ti][tj][r]);
            }
        __syncthreads();
        #pragma unroll
        for (int i = 0; i < 8; ++i) {
            int idx = t + i * 256;
            int row = idx >> 4, c16 = idx & 15;
            int n = base + row;
            if (n < N_NODES) {
                uint4 v = *(const uint4*)(smem + row * TSTR + c16 * 8);
                *(uint4*)(cf_a + (size_t)n * HD + c16 * 8) = v;
            }
        }
    }
}

// ---------------------------------------------------------------------------
// Pipelined barrier-free MFMA edge pass: msg = leaky([cf[f]|cf[t]|ef]@W.T + b)
// 256 edges x 128 ch per block; 8 waves 4x2 (64x64 each); K = 9x32.
// Ordering (the round-11 fix): W-staging loads issued FIRST, then chunks 0-1
// of A prefetched (drained together by the barrier), then a depth-2 rotating
// prefetch inside the unrolled K-loop: while chunk c computes, chunks c+1 and
// c+2 are in flight. 3 A-register sets = 48 VGPR -> fits the (512,4) 128-cap,
// so occupancy stays at the LDS-limited 2 blocks/CU (unlike round 11).
// REDUCE: single-phase 256-row LDS transpose + in-LDS per-from-node segmax.
// ---------------------------------------------------------------------------
template<int REDUCE>
__global__ __launch_bounds__(512, 4) void edge_mfma(
    const u16* __restrict__ cfb,
    const int* __restrict__ from_p,
    const int* __restrict__ to_p,
    const uint2* __restrict__ efb_p,
    const u16* __restrict__ Wb,
    const float* __restrict__ bias,
    const int* __restrict__ offs,
    const int* __restrict__ cnt,
    u16* __restrict__ cf_bb,
    float* __restrict__ cf_b32,
    int* __restrict__ ipf_out)
{
    __shared__ __align__(16) u16 smem[128 * WSTR];   // 75776 B (W; reused 256xTSTR)
    __shared__ int colmax_s[128];

    const int t    = threadIdx.x;
    const int base = blockIdx.x * 256;          // 1250 blocks exact
    const int wave = t >> 6, l = t & 63;
    const int quad = l >> 4, lc = l & 15;
    const int R0 = (wave >> 1) * 64;
    const int C0 = (wave & 1) * 64;

    if (t < 128) colmax_s[t] = 0;

    // 1) stage W into LDS (loads issued first)
    for (int idx = t; idx < 128 * 36; idx += 512) {
        int r = idx / 36, j = idx - r * 36;
        ((uint4*)(smem + r * WSTR))[j] = ((const uint4*)(Wb + (size_t)r * KPAD))[j];
    }

    // 2) edge metadata + prefetch chunks 0,1 of A (hidden under staging drain)
    int nf[4], nt[4]; uint2 efr[4];
    #pragma unroll
    for (int ti = 0; ti < 4; ++ti) {
        int e = base + R0 + ti * 16 + lc;
        nf[ti]  = from_p[e];
        nt[ti]  = to_p[e];
        efr[ti] = efb_p[e];
    }
    bf16x8 apre[3][4];                      // rotating depth-2 pipeline
    #pragma unroll
    for (int c = 0; c < 2; ++c)
        #pragma unroll
        for (int ti = 0; ti < 4; ++ti)
            apre[c][ti] = *(const bf16x8*)(cfb + nf[ti] * HD + c * 32 + quad * 8);

    __syncthreads();   // W resident (+ chunk 0,1 A in regs)

    f32x4 acc[4][4];
    #pragma unroll
    for (int i = 0; i < 4; ++i)
        #pragma unroll
        for (int j = 0; j < 4; ++j) acc[i][j] = (f32x4){0.f, 0.f, 0.f, 0.f};

    // 3) K-loop with depth-2 rotating prefetch
    #pragma unroll
    for (int c = 0; c < 8; ++c) {
        if (c + 2 < 8) {
            const int cn = c + 2;
            #pragma unroll
            for (int ti = 0; ti < 4; ++ti) {
                int node = (cn < 4) ? nf[ti] : nt[ti];
                apre[cn % 3][ti] = *(const bf16x8*)(cfb + node * HD + (cn & 3) * 32 + quad * 8);
            }
        }
        bf16x8 bfr[4];
        #pragma unroll
        for (int tj = 0; tj < 4; ++tj)
            bfr[tj] = *(const bf16x8*)(smem + (C0 + tj * 16 + lc) * WSTR + c * 32 + quad * 8);
        #pragma unroll
        for (int ti = 0; ti < 4; ++ti)
            #pragma unroll
            for (int tj = 0; tj < 4; ++tj)
                acc[ti][tj] = __builtin_amdgcn_mfma_f32_16x16x32_bf16(
                    apre[c % 3][ti], bfr[tj], acc[ti][tj], 0, 0, 0);
    }
    {   // chunk 8: edge-type features (k 256..259 real, rest zero)
        bf16x8 af[4], bfr[4];
        #pragma unroll
        for (int ti = 0; ti < 4; ++ti) {
            union { bf16x8 v; unsigned u[4]; } p;
            p.u[0] = efr[ti].x; p.u[1] = efr[ti].y; p.u[2] = 0u; p.u[3] = 0u;
            union { bf16x8 v; unsigned u[4]; } z;
            z.u[0] = z.u[1] = z.u[2] = z.u[3] = 0u;
            af[ti] = (quad == 0) ? p.v : z.v;
        }
        #pragma unroll
        for (int tj = 0; tj < 4; ++tj)
            bfr[tj] = *(const bf16x8*)(smem + (C0 + tj * 16 + lc) * WSTR + 8 * 32 + quad * 8);
        #pragma unroll
        for (int ti = 0; ti < 4; ++ti)
            #pragma unroll
            for (int tj = 0; tj < 4; ++tj)
                acc[ti][tj] = __builtin_amdgcn_mfma_f32_16x16x32_bf16(
                    af[ti], bfr[tj], acc[ti][tj], 0, 0, 0);
    }

    // bias + leaky; per-channel block max
    #pragma unroll
    for (int tj = 0; tj < 4; ++tj) {
        const int col = C0 + tj * 16 + lc;
        const float bc = bias[col];
        float mx = 0.f;
        #pragma unroll
        for (int ti = 0; ti < 4; ++ti) {
            #pragma unroll
            for (int r = 0; r < 4; ++r) {
                float x = leaky(acc[ti][tj][r] + bc);
                acc[ti][tj][r] = x;
                mx = fmaxf(mx, x);
            }
        }
        atomicMax(&colmax_s[col], __float_as_int(mx));
    }
    __syncthreads();   // colmax done; W reads drained (smem reusable)
    if (t < 128) atomicMax(&ipf_out[t], colmax_s[t]);

    if (REDUCE) {
        // single-phase transpose of all 256 rows (256*TSTR*2 = 69632 B fits)
        #pragma unroll
        for (int ti = 0; ti < 4; ++ti)
            #pragma unroll
            for (int tj = 0; tj < 4; ++tj) {
                const int col = C0 + tj * 16 + lc;
                #pragma unroll
                for (int r = 0; r < 4; ++r)
                    smem[(R0 + ti * 16 + quad * 4 + r) * TSTR + col] = f2bf(acc[ti][tj][r]);
            }
        __syncthreads();
        // in-LDS per-from-node segment max (rows CSR-contiguous)
        const int nfirst = from_p[base];
        const int nlast  = from_p[base + 255];
        const int ch = t & 127;
        for (int n = nfirst + (t >> 7); n <= nlast; n += 4) {
            int o = offs[n], c = cnt[n];
            int lo = o - base, hi = o + c - base;
            int lo2 = lo > 0 ? lo : 0;
            int hi2 = hi < 256 ? hi : 256;
            if (lo2 >= hi2) continue;
            float m = 0.f;       // 0 floor matches zeros.at[].max
            for (int r = lo2; r < hi2; ++r)
                m = fmaxf(m, bf2f(smem[r * TSTR + ch]));
            if (lo >= 0 && hi <= 256)
                cf_bb[(size_t)n * HD + ch] = f2bf(m);
            else
                atomicMax((int*)&cf_b32[(size_t)n * HD + ch], __float_as_int(m));
        }
    }
}

// ---------------------------------------------------------------------------
__global__ __launch_bounds__(256) void fixup(
    const int* __restrict__ offs, const int* __restrict__ cnt,
    const float* __restrict__ cf_b32, u16* __restrict__ cf_bb)
{
    const int n = blockIdx.x * 2 + (threadIdx.x >> 7);
    const int ch = threadIdx.x & 127;
    int o = offs[n], c = cnt[n];
    if (c > 0 && (o >> 8) != ((o + c - 1) >> 8))
        cf_bb[(size_t)n * HD + ch] = f2bf(cf_b32[(size_t)n * HD + ch]);
}

// ---------------------------------------------------------------------------
__global__ __launch_bounds__(128) void heads(
    const unsigned* __restrict__ ipf0_m,
    const float* __restrict__ ipf1, const float* __restrict__ ipf2,
    const float* __restrict__ secW, const float* __restrict__ secB,
    const unsigned* __restrict__ pg_m, const unsigned* __restrict__ sg_m,
    const float* __restrict__ geoW, const float* __restrict__ geoB,
    const float* __restrict__ gnw, const float* __restrict__ gnb,
    float* __restrict__ out)
{
    const int t = threadIdx.x;
    if (blockIdx.x == 0) {
        __shared__ float s[384];
        s[t]       = funmap(ipf0_m[t]);
        s[128 + t] = ipf1[t];
        s[256 + t] = ipf2[t];
        __syncthreads();
        float acc = secB[t];
        #pragma unroll 4
        for (int k = 0; k < 384; ++k) acc = fmaf(s[k], secW[t*384 + k], acc);
        out[t] = leaky(acc);
    } else {
        __shared__ float pg[128];
        __shared__ float tt[128];
        pg[t] = leaky(funmap(pg_m[t]));
        float sg = leaky(funmap(sg_m[t]));
        __syncthreads();
        float acc = geoB[t];
        #pragma unroll 4
        for (int k = 0; k < 128; ++k) acc = fmaf(pg[k], geoW[t*128 + k], acc);
        tt[t] = acc;
        __syncthreads();
        const int g = (t >> 3) << 3;
        float mu = 0.f, m2 = 0.f;
        #pragma unroll
        for (int q = 0; q < 8; ++q) { float x = tt[g + q]; mu += x; m2 += x*x; }
        mu *= 0.125f;
        m2 = m2 * 0.125f - mu * mu;
        float xn = (acc - mu) * rsqrtf(m2 + 1e-5f);
        out[128 + t] = leaky(sg + xn * gnw[t] + gnb[t]);
    }
}

// ---------------------------------------------------------------------------
extern "C" void kernel_launch(void* const* d_in, const int* in_sizes, int n_in,
                              void* d_out, int out_size, void* d_ws, size_t ws_size,
                              hipStream_t stream)
{
    const float* child_feats  = (const float*)d_in[0];
    const float* child_geo    = (const float*)d_in[1];
    const float* child_exists = (const float*)d_in[2];
    const float* etoh         = (const float*)d_in[3];
    const int*   eidx         = (const int*)  d_in[4];
    const float* op_w   = (const float*)d_in[5];
    const float* op_b   = (const float*)d_in[6];
    const float* sec_w  = (const float*)d_in[7];
    const float* sec_b  = (const float*)d_in[8];
    const float* edge_w = (const float*)d_in[9];
    const float* edge_b = (const float*)d_in[10];
    const float* geo_w  = (const float*)d_in[11];
    const float* geo_b  = (const float*)d_in[12];
    const float* sgeo_w = (const float*)d_in[13];
    const float* sgeo_b = (const float*)d_in[14];
    const float* gn_w   = (const float*)d_in[15];
    const float* gn_b   = (const float*)d_in[16];
    const float* skip_w = (const float*)d_in[17];
    const float* skip_b = (const float*)d_in[18];
    float* out = (float*)d_out;

    // workspace layout (all offsets 16B aligned)
    char* ws = (char*)d_ws;
    size_t off = 0;
    u16*   cf_a   = (u16*)(ws + off);   off += (size_t)N_NODES*HD*2;
    u16*   featsb = (u16*)(ws + off);   off += (size_t)N_NODES*KOP*2;
    u16*   geob   = (u16*)(ws + off);   off += (size_t)N_NODES*HD*2;
    u16*   Wb     = (u16*)(ws + off);   off += (size_t)2*128*KPAD*2;
    u16*   Wop    = (u16*)(ws + off);   off += (size_t)128*KOP*2;
    u16*   Wgeo   = (u16*)(ws + off);   off += (size_t)128*128*2;
    u16*   Wskip  = (u16*)(ws + off);   off += (size_t)128*128*2;
    int*   from_p = (int*)(ws + off);   off += (size_t)N_EDGES*4;
    int*   to_p   = (int*)(ws + off);   off += (size_t)N_EDGES*4;
    uint2* efb_p  = (uint2*)(ws + off); off += (size_t)N_EDGES*8;
    int*   offs   = (int*)(ws + off);   off += (size_t)N_NODES*4;
    char*  zero0  = ws + off;
    u16*   cf_bb  = (u16*)(ws + off);         off += (size_t)N_NODES*HD*2;
    float* cf_b32 = (float*)(ws + off);       off += (size_t)N_NODES*HD*4;
    unsigned* ipf0_m = (unsigned*)(ws + off); off += 128*4;
    float*    ipf1   = (float*)(ws + off);    off += 128*4;
    float*    ipf2   = (float*)(ws + off);    off += 128*4;
    unsigned* pg_m   = (unsigned*)(ws + off); off += 128*4;
    unsigned* sg_m   = (unsigned*)(ws + off); off += 128*4;
    int*      count  = (int*)(ws + off);      off += (size_t)N_NODES*4;
    int*      cursor = (int*)(ws + off);      off += (size_t)N_NODES*4;
    size_t zero_bytes = (size_t)(ws + off - zero0);

    hipMemsetAsync(zero0, 0, zero_bytes, stream);

    prep<<<PREP_GRID, 256, 0, stream>>>(
        edge_w, Wb, op_w, Wop, geo_w, Wgeo, skip_w, Wskip,
        child_feats, featsb, child_geo, geob, eidx, count);

    scan_offsets<<<1, 1024, 0, stream>>>(count, offs);

    // fill_perm + node GEMMs in one launch
    mid<<<1721, 256, 0, stream>>>(
        eidx, etoh, offs, cursor, from_p, to_p, efb_p,
        featsb, geob, child_exists, Wop, op_b, Wgeo, geo_b, Wskip, skip_b,
        cf_a, ipf0_m, pg_m, sg_m);

    // iter 1: pipelined MFMA messages + fused in-LDS segment max
    edge_mfma<1><<<N_EDGES/256, 512, 0, stream>>>(
        cf_a, from_p, to_p, efb_p, Wb, edge_b,
        offs, count, cf_bb, cf_b32, (int*)ipf1);

    fixup<<<N_NODES/2, 256, 0, stream>>>(offs, count, cf_b32, cf_bb);

    // iter 2: only column max needed
    edge_mfma<0><<<N_EDGES/256, 512, 0, stream>>>(
        cf_bb, from_p, to_p, efb_p, Wb + 128*KPAD, edge_b + 128,
        offs, count, nullptr, nullptr, (int*)ipf2);

    heads<<<2, 128, 0, stream>>>(ipf0_m, ipf1, ipf2, sec_w, sec_b,
                                 pg_m, sg_m, sgeo_w, sgeo_b, gn_w, gn_b, out);
}

// Round 13
// 314.055 us; speedup vs baseline: 1.1751x; 1.1751x over previous
//
#include <hip/hip_runtime.h>

#define N_NODES 20000
#define N_EDGES 320000
#define HD 128
#define FIN 162      // 24 + 10 + 128
#define KE 260       // 2*H + ETN
#define KPAD 288     // edge K padded: 9 chunks of 32
#define KOP 192      // encode K padded: 6 chunks of 32
#define WSTR 296     // edge W LDS row stride (u16): 592B
#define OSTR 200     // encode W LDS row stride (u16)
#define GSTR 136     // geo W LDS row stride (u16)
#define TSTR 136     // transpose row stride (u16): 128 ch + 8 pad

typedef unsigned short u16;
typedef __attribute__((ext_vector_type(8))) short bf16x8;
typedef __attribute__((ext_vector_type(4))) float f32x4;

__device__ __forceinline__ float leaky(float x){ return x > 0.f ? x : 0.01f*x; }
__device__ __forceinline__ unsigned fmap(float f){
    unsigned u = __float_as_uint(f);
    return (u & 0x80000000u) ? ~u : (u | 0x80000000u);
}
__device__ __forceinline__ float funmap(unsigned u){
    return __uint_as_float((u & 0x80000000u) ? (u & 0x7fffffffu) : ~u);
}
__device__ __forceinline__ unsigned umax_(unsigned a, unsigned b){ return a > b ? a : b; }
__device__ __forceinline__ u16 f2bf(float x){
    unsigned b = __float_as_uint(x);
    return (u16)((b + 0x7fffu + ((b >> 16) & 1u)) >> 16);
}
__device__ __forceinline__ float bf2f(u16 u){
    return __uint_as_float(((unsigned)u) << 16);
}

// ---------------------------------------------------------------------------
// prep: fully-vectorized bf16 conversions + from-histogram
// ---------------------------------------------------------------------------
#define PB_W 16
#define PB_F 960
#define PB_G 640
#define PB_H 320
#define PREP_GRID (PB_W + PB_F + PB_G + PB_H)

__global__ __launch_bounds__(256) void prep(
    const float* __restrict__ edge_w, u16* __restrict__ Wb,
    const float* __restrict__ op_w,   u16* __restrict__ Wop,
    const float* __restrict__ geo_w,  u16* __restrict__ Wgeo,
    const float* __restrict__ skip_w, u16* __restrict__ Wskip,
    const float* __restrict__ feats,  u16* __restrict__ featsb,
    const float* __restrict__ geof,   u16* __restrict__ geob,
    const int* __restrict__ eidx, int* __restrict__ count)
{
    const int b = blockIdx.x, t = threadIdx.x;
    if (b < PB_W) {
        for (int idx = b * 256 + t; idx < 16384; idx += PB_W * 256) {
            union { u16 us[8]; uint4 v; } pk;
            if (idx < 9216) {
                int layer = idx / 4608, rem = idx - layer * 4608;
                int h = rem / 36, j = rem - h * 36;
                const float* src = edge_w + (size_t)layer * 128 * KE + h * KE;
                #pragma unroll
                for (int kk = 0; kk < 8; ++kk) {
                    int k = j * 8 + kk;
                    pk.us[kk] = (k < KE) ? f2bf(src[k]) : (u16)0;
                }
                ((uint4*)Wb)[(size_t)layer * 128 * 36 + h * 36 + j] = pk.v;
            } else if (idx < 12288) {
                int rem = idx - 9216;
                int h = rem / 24, j = rem - h * 24;
                const float* src = op_w + h * FIN;
                #pragma unroll
                for (int kk = 0; kk < 8; ++kk) {
                    int k = j * 8 + kk;
                    pk.us[kk] = (k < FIN) ? f2bf(src[k]) : (u16)0;
                }
                ((uint4*)Wop)[h * 24 + j] = pk.v;
            } else {
                int rem = idx - 12288;
                int which = rem >> 11;
                int r2 = rem & 2047;
                const float4* src = (const float4*)((which ? skip_w : geo_w)) + r2 * 2;
                float4 a = src[0], c = src[1];
                pk.us[0]=f2bf(a.x); pk.us[1]=f2bf(a.y); pk.us[2]=f2bf(a.z); pk.us[3]=f2bf(a.w);
                pk.us[4]=f2bf(c.x); pk.us[5]=f2bf(c.y); pk.us[6]=f2bf(c.z); pk.us[7]=f2bf(c.w);
                ((uint4*)(which ? Wskip : Wgeo))[r2] = pk.v;
            }
        }
    } else if (b < PB_W + PB_F) {
        for (int f = (b - PB_W) * 256 + t; f < N_NODES * 24; f += PB_F * 256) {
            int n = f / 24, j = f - n * 24;
            union { u16 us[8]; uint4 v; } pk;
            if (j < 20) {
                const float2* src = (const float2*)(feats + (size_t)n * FIN + j * 8);
                float2 p0 = src[0], p1 = src[1], p2 = src[2], p3 = src[3];
                pk.us[0]=f2bf(p0.x); pk.us[1]=f2bf(p0.y); pk.us[2]=f2bf(p1.x); pk.us[3]=f2bf(p1.y);
                pk.us[4]=f2bf(p2.x); pk.us[5]=f2bf(p2.y); pk.us[6]=f2bf(p3.x); pk.us[7]=f2bf(p3.y);
            } else if (j == 20) {
                float2 p = *(const float2*)(feats + (size_t)n * FIN + 160);
                pk.us[0]=f2bf(p.x); pk.us[1]=f2bf(p.y);
                pk.us[2]=pk.us[3]=pk.us[4]=pk.us[5]=pk.us[6]=pk.us[7]=0;
            } else {
                #pragma unroll
                for (int kk = 0; kk < 8; ++kk) pk.us[kk] = 0;
            }
            ((uint4*)featsb)[(size_t)n * 24 + j] = pk.v;
        }
    } else if (b < PB_W + PB_F + PB_G) {
        for (int g = (b - PB_W - PB_F) * 256 + t; g < N_NODES * 16; g += PB_G * 256) {
            const float4* s = (const float4*)geof + (size_t)g * 2;
            float4 a = s[0], c = s[1];
            union { u16 us[8]; uint4 v; } pk;
            pk.us[0]=f2bf(a.x); pk.us[1]=f2bf(a.y); pk.us[2]=f2bf(a.z); pk.us[3]=f2bf(a.w);
            pk.us[4]=f2bf(c.x); pk.us[5]=f2bf(c.y); pk.us[6]=f2bf(c.z); pk.us[7]=f2bf(c.w);
            ((uint4*)geob)[g] = pk.v;
        }
    } else {
        for (int e = (b - PB_W - PB_F - PB_G) * 256 + t; e < N_EDGES; e += PB_H * 256)
            atomicAdd(&count[eidx[2 * e]], 1);
    }
}

// ---------------------------------------------------------------------------
__global__ __launch_bounds__(1024) void scan_offsets(
    const int* __restrict__ count, int* __restrict__ offset)
{
    __shared__ int part[1024];
    const int t = threadIdx.x;
    const int lo = t * 20;
    const int hi = min(lo + 20, N_NODES);
    int s = 0;
    for (int n = lo; n < hi; ++n) s += count[n];
    part[t] = s;
    __syncthreads();
    for (int d = 1; d < 1024; d <<= 1) {
        int v = (t >= d) ? part[t - d] : 0;
        __syncthreads();
        part[t] += v;
        __syncthreads();
    }
    int run = (t > 0) ? part[t - 1] : 0;
    for (int n = lo; n < hi; ++n) { offset[n] = run; run += count[n]; }
}

// ---------------------------------------------------------------------------
// mid: blocks [0,1250) fill_perm | [1250,1721) node MFMA
// ---------------------------------------------------------------------------
__global__ __launch_bounds__(256) void mid(
    const int* __restrict__ eidx, const float* __restrict__ ef,
    const int* __restrict__ offset, int* __restrict__ cursor,
    int* __restrict__ from_p, int* __restrict__ to_p, uint2* __restrict__ efb_p,
    const u16* __restrict__ featsb, const u16* __restrict__ geob,
    const float* __restrict__ exists,
    const u16* __restrict__ Wop, const float* __restrict__ op_b,
    const u16* __restrict__ Wgeo, const float* __restrict__ geo_b,
    const u16* __restrict__ Wskip, const float* __restrict__ skip_b,
    u16* __restrict__ cf_a,
    unsigned* __restrict__ ipf0_m, unsigned* __restrict__ pg_m,
    unsigned* __restrict__ sg_m)
{
    __shared__ __align__(16) u16 smem[128 * OSTR];   // 51200 B
    __shared__ float ex_s[128];
    __shared__ unsigned colmax_s[128];

    const int blk = blockIdx.x, t = threadIdx.x;
    if (blk < 1250) {
        int e = blk * 256 + t;
        int2 p = ((const int2*)eidx)[e];
        int pos = offset[p.x] + atomicAdd(&cursor[p.x], 1);
        from_p[pos] = p.x; to_p[pos] = p.y;
        float4 e4 = ((const float4*)ef)[e];
        efb_p[pos] = make_uint2(
            (unsigned)f2bf(e4.x) | ((unsigned)f2bf(e4.y) << 16),
            (unsigned)f2bf(e4.z) | ((unsigned)f2bf(e4.w) << 16));
        return;
    }
    const int b = blk - 1250;
    const int mode = (b < 157) ? 0 : (b < 314) ? 1 : 2;
    const int bx = b - (mode == 0 ? 0 : mode == 1 ? 157 : 314);
    const int base = bx * 128;
    const int wave = t >> 6, l = t & 63;
    const int quad = l >> 4, lc = l & 15;
    const int R0 = (wave >> 1) * 64;
    const int C0 = (wave & 1) * 64;

    const u16* W = (mode == 0) ? Wop : (mode == 1) ? Wgeo : Wskip;
    const float* bias = (mode == 0) ? op_b : (mode == 1) ? geo_b : skip_b;
    unsigned* accout = (mode == 0) ? ipf0_m : (mode == 1) ? pg_m : sg_m;
    const int KW = (mode == 0) ? KOP : HD;
    const int SW = (mode == 0) ? OSTR : GSTR;
    const int NCH = (mode == 0) ? 6 : 4;
    const u16* A = (mode == 0) ? featsb : geob;

    {
        const int r = t >> 1, half = t & 1;
        const int nu4 = KW / 16;
        const uint4* src = (const uint4*)(W + (size_t)r * KW) + half * nu4;
        uint4* dst = (uint4*)(smem + r * SW) + half * nu4;
        for (int i = 0; i < nu4; ++i) dst[i] = src[i];
    }
    if (t < 128) {
        int n = base + t; if (n >= N_NODES) n = N_NODES - 1;
        ex_s[t] = exists[n];
        colmax_s[t] = 0u;
    }
    __syncthreads();

    f32x4 acc[4][4];
    #pragma unroll
    for (int i = 0; i < 4; ++i)
        #pragma unroll
        for (int j = 0; j < 4; ++j) acc[i][j] = (f32x4){0.f, 0.f, 0.f, 0.f};

    int nd[4];
    #pragma unroll
    for (int ti = 0; ti < 4; ++ti) {
        int n = base + R0 + ti * 16 + lc;
        nd[ti] = (n < N_NODES) ? n : N_NODES - 1;
    }

    for (int c = 0; c < NCH; ++c) {
        bf16x8 af[4], bfr[4];
        #pragma unroll
        for (int ti = 0; ti < 4; ++ti)
            af[ti] = *(const bf16x8*)(A + (size_t)nd[ti] * KW + c * 32 + quad * 8);
        #pragma unroll
        for (int tj = 0; tj < 4; ++tj)
            bfr[tj] = *(const bf16x8*)(smem + (C0 + tj * 16 + lc) * SW + c * 32 + quad * 8);
        #pragma unroll
        for (int ti = 0; ti < 4; ++ti)
            #pragma unroll
            for (int tj = 0; tj < 4; ++tj)
                acc[ti][tj] = __builtin_amdgcn_mfma_f32_16x16x32_bf16(
                    af[ti], bfr[tj], acc[ti][tj], 0, 0, 0);
    }

    #pragma unroll
    for (int tj = 0; tj < 4; ++tj) {
        const int col = C0 + tj * 16 + lc;
        const float bc = bias[col];
        unsigned mx = 0u;
        #pragma unroll
        for (int ti = 0; ti < 4; ++ti) {
            #pragma unroll
            for (int r = 0; r < 4; ++r) {
                int row = R0 + ti * 16 + quad * 4 + r;
                float x = (acc[ti][tj][r] + bc) * ex_s[row];
                acc[ti][tj][r] = x;
                mx = umax_(mx, fmap(x));
            }
        }
        atomicMax(&colmax_s[col], mx);
    }
    __syncthreads();
    if (t < 128) atomicMax(&accout[t], colmax_s[t]);

    if (mode == 0) {
        #pragma unroll
        for (int ti = 0; ti < 4; ++ti)
            #pragma unroll
            for (int tj = 0; tj < 4; ++tj) {
                const int col = C0 + tj * 16 + lc;
                #pragma unroll
                for (int r = 0; r < 4; ++r)
                    smem[(R0 + ti * 16 + quad * 4 + r) * TSTR + col] = f2bf(acc[ti][tj][r]);
            }
        __syncthreads();
        #pragma unroll
        for (int i = 0; i < 8; ++i) {
            int idx = t + i * 256;
            int row = idx >> 4, c16 = idx & 15;
            int n = base + row;
            if (n < N_NODES) {
                uint4 v = *(const uint4*)(smem + row * TSTR + c16 * 8);
                *(uint4*)(cf_a + (size_t)n * HD + c16 * 8) = v;
            }
        }
    }
}

// ---------------------------------------------------------------------------
// Barrier-free MFMA edge pass (round-9 form — the measured best):
// 256 edges x 128 ch per block; 8 waves 4x2 (64x64 each); K = 9x32.
// Per-chunk A gathers issued inside the K-loop (compiler overlaps next-chunk
// loads under MFMA latency; no explicit prefetch — r11/r12 showed any manual
// pipeline either spills (VGPR cap 64/128) or serializes at the barrier).
// W in LDS once (1 barrier). REDUCE: single-phase 256-row LDS transpose +
// in-LDS per-from-node segmax; interior -> bf16 stores, boundary -> atomics.
// ---------------------------------------------------------------------------
template<int REDUCE>
__global__ __launch_bounds__(512, 4) void edge_mfma(
    const u16* __restrict__ cfb,
    const int* __restrict__ from_p,
    const int* __restrict__ to_p,
    const uint2* __restrict__ efb_p,
    const u16* __restrict__ Wb,
    const float* __restrict__ bias,
    const int* __restrict__ offs,
    const int* __restrict__ cnt,
    u16* __restrict__ cf_bb,
    float* __restrict__ cf_b32,
    int* __restrict__ ipf_out)
{
    __shared__ __align__(16) u16 smem[128 * WSTR];   // 75776 B (W; reused 256xTSTR)
    __shared__ int colmax_s[128];

    const int t    = threadIdx.x;
    const int base = blockIdx.x * 256;          // 1250 blocks exact
    const int wave = t >> 6, l = t & 63;
    const int quad = l >> 4, lc = l & 15;
    const int R0 = (wave >> 1) * 64;
    const int C0 = (wave & 1) * 64;

    // stage full W into LDS
    for (int idx = t; idx < 128 * 36; idx += 512) {
        int r = idx / 36, j = idx - r * 36;
        ((uint4*)(smem + r * WSTR))[j] = ((const uint4*)(Wb + (size_t)r * KPAD))[j];
    }
    if (t < 128) colmax_s[t] = 0;

    int nf[4], nt[4]; uint2 efr[4];
    #pragma unroll
    for (int ti = 0; ti < 4; ++ti) {
        int e = base + R0 + ti * 16 + lc;
        nf[ti]  = from_p[e];
        nt[ti]  = to_p[e];
        efr[ti] = efb_p[e];
    }
    __syncthreads();   // W resident

    f32x4 acc[4][4];
    #pragma unroll
    for (int i = 0; i < 4; ++i)
        #pragma unroll
        for (int j = 0; j < 4; ++j) acc[i][j] = (f32x4){0.f, 0.f, 0.f, 0.f};

    #pragma unroll
    for (int c = 0; c < 8; ++c) {
        bf16x8 af[4], bfr[4];
        #pragma unroll
        for (int ti = 0; ti < 4; ++ti) {
            int node = (c < 4) ? nf[ti] : nt[ti];
            af[ti] = *(const bf16x8*)(cfb + node * HD + (c & 3) * 32 + quad * 8);
        }
        #pragma unroll
        for (int tj = 0; tj < 4; ++tj)
            bfr[tj] = *(const bf16x8*)(smem + (C0 + tj * 16 + lc) * WSTR + c * 32 + quad * 8);
        #pragma unroll
        for (int ti = 0; ti < 4; ++ti)
            #pragma unroll
            for (int tj = 0; tj < 4; ++tj)
                acc[ti][tj] = __builtin_amdgcn_mfma_f32_16x16x32_bf16(
                    af[ti], bfr[tj], acc[ti][tj], 0, 0, 0);
    }
    {   // chunk 8: edge-type features (k 256..259 real, rest zero)
        bf16x8 af[4], bfr[4];
        #pragma unroll
        for (int ti = 0; ti < 4; ++ti) {
            union { bf16x8 v; unsigned u[4]; } p;
            p.u[0] = efr[ti].x; p.u[1] = efr[ti].y; p.u[2] = 0u; p.u[3] = 0u;
            union { bf16x8 v; unsigned u[4]; } z;
            z.u[0] = z.u[1] = z.u[2] = z.u[3] = 0u;
            af[ti] = (quad == 0) ? p.v : z.v;
        }
        #pragma unroll
        for (int tj = 0; tj < 4; ++tj)
            bfr[tj] = *(const bf16x8*)(smem + (C0 + tj * 16 + lc) * WSTR + 8 * 32 + quad * 8);
        #pragma unroll
        for (int ti = 0; ti < 4; ++ti)
            #pragma unroll
            for (int tj = 0; tj < 4; ++tj)
                acc[ti][tj] = __builtin_amdgcn_mfma_f32_16x16x32_bf16(
                    af[ti], bfr[tj], acc[ti][tj], 0, 0, 0);
    }

    // bias + leaky; per-channel block max
    #pragma unroll
    for (int tj = 0; tj < 4; ++tj) {
        const int col = C0 + tj * 16 + lc;
        const float bc = bias[col];
        float mx = 0.f;
        #pragma unroll
        for (int ti = 0; ti < 4; ++ti) {
            #pragma unroll
            for (int r = 0; r < 4; ++r) {
                float x = leaky(acc[ti][tj][r] + bc);
                acc[ti][tj][r] = x;
                mx = fmaxf(mx, x);
            }
        }
        atomicMax(&colmax_s[col], __float_as_int(mx));
    }
    __syncthreads();   // colmax done; W reads drained (smem reusable)
    if (t < 128) atomicMax(&ipf_out[t], colmax_s[t]);

    if (REDUCE) {
        // single-phase transpose of all 256 rows (256*TSTR*2 = 69632 B fits)
        #pragma unroll
        for (int ti = 0; ti < 4; ++ti)
            #pragma unroll
            for (int tj = 0; tj < 4; ++tj) {
                const int col = C0 + tj * 16 + lc;
                #pragma unroll
                for (int r = 0; r < 4; ++r)
                    smem[(R0 + ti * 16 + quad * 4 + r) * TSTR + col] = f2bf(acc[ti][tj][r]);
            }
        __syncthreads();
        // in-LDS per-from-node segment max (rows CSR-contiguous)
        const int nfirst = from_p[base];
        const int nlast  = from_p[base + 255];
        const int ch = t & 127;
        for (int n = nfirst + (t >> 7); n <= nlast; n += 4) {
            int o = offs[n], c = cnt[n];
            int lo = o - base, hi = o + c - base;
            int lo2 = lo > 0 ? lo : 0;
            int hi2 = hi < 256 ? hi : 256;
            if (lo2 >= hi2) continue;
            float m = 0.f;       // 0 floor matches zeros.at[].max
            for (int r = lo2; r < hi2; ++r)
                m = fmaxf(m, bf2f(smem[r * TSTR + ch]));
            if (lo >= 0 && hi <= 256)
                cf_bb[(size_t)n * HD + ch] = f2bf(m);
            else
                atomicMax((int*)&cf_b32[(size_t)n * HD + ch], __float_as_int(m));
        }
    }
}

// ---------------------------------------------------------------------------
__global__ __launch_bounds__(256) void fixup(
    const int* __restrict__ offs, const int* __restrict__ cnt,
    const float* __restrict__ cf_b32, u16* __restrict__ cf_bb)
{
    const int n = blockIdx.x * 2 + (threadIdx.x >> 7);
    const int ch = threadIdx.x & 127;
    int o = offs[n], c = cnt[n];
    if (c > 0 && (o >> 8) != ((o + c - 1) >> 8))
        cf_bb[(size_t)n * HD + ch] = f2bf(cf_b32[(size_t)n * HD + ch]);
}

// ---------------------------------------------------------------------------
__global__ __launch_bounds__(128) void heads(
    const unsigned* __restrict__ ipf0_m,
    const float* __restrict__ ipf1, const float* __restrict__ ipf2,
    const float* __restrict__ secW, const float* __restrict__ secB,
    const unsigned* __restrict__ pg_m, const unsigned* __restrict__ sg_m,
    const float* __restrict__ geoW, const float* __restrict__ geoB,
    const float* __restrict__ gnw, const float* __restrict__ gnb,
    float* __restrict__ out)
{
    const int t = threadIdx.x;
    if (blockIdx.x == 0) {
        __shared__ float s[384];
        s[t]       = funmap(ipf0_m[t]);
        s[128 + t] = ipf1[t];
        s[256 + t] = ipf2[t];
        __syncthreads();
        float acc = secB[t];
        #pragma unroll 4
        for (int k = 0; k < 384; ++k) acc = fmaf(s[k], secW[t*384 + k], acc);
        out[t] = leaky(acc);
    } else {
        __shared__ float pg[128];
        __shared__ float tt[128];
        pg[t] = leaky(funmap(pg_m[t]));
        float sg = leaky(funmap(sg_m[t]));
        __syncthreads();
        float acc = geoB[t];
        #pragma unroll 4
        for (int k = 0; k < 128; ++k) acc = fmaf(pg[k], geoW[t*128 + k], acc);
        tt[t] = acc;
        __syncthreads();
        const int g = (t >> 3) << 3;
        float mu = 0.f, m2 = 0.f;
        #pragma unroll
        for (int q = 0; q < 8; ++q) { float x = tt[g + q]; mu += x; m2 += x*x; }
        mu *= 0.125f;
        m2 = m2 * 0.125f - mu * mu;
        float xn = (acc - mu) * rsqrtf(m2 + 1e-5f);
        out[128 + t] = leaky(sg + xn * gnw[t] + gnb[t]);
    }
}

// ---------------------------------------------------------------------------
extern "C" void kernel_launch(void* const* d_in, const int* in_sizes, int n_in,
                              void* d_out, int out_size, void* d_ws, size_t ws_size,
                              hipStream_t stream)
{
    const float* child_feats  = (const float*)d_in[0];
    const float* child_geo    = (const float*)d_in[1];
    const float* child_exists = (const float*)d_in[2];
    const float* etoh         = (const float*)d_in[3];
    const int*   eidx         = (const int*)  d_in[4];
    const float* op_w   = (const float*)d_in[5];
    const float* op_b   = (const float*)d_in[6];
    const float* sec_w  = (const float*)d_in[7];
    const float* sec_b  = (const float*)d_in[8];
    const float* edge_w = (const float*)d_in[9];
    const float* edge_b = (const float*)d_in[10];
    const float* geo_w  = (const float*)d_in[11];
    const float* geo_b  = (const float*)d_in[12];
    const float* sgeo_w = (const float*)d_in[13];
    const float* sgeo_b = (const float*)d_in[14];
    const float* gn_w   = (const float*)d_in[15];
    const float* gn_b   = (const float*)d_in[16];
    const float* skip_w = (const float*)d_in[17];
    const float* skip_b = (const float*)d_in[18];
    float* out = (float*)d_out;

    // workspace layout (all offsets 16B aligned)
    char* ws = (char*)d_ws;
    size_t off = 0;
    u16*   cf_a   = (u16*)(ws + off);   off += (size_t)N_NODES*HD*2;
    u16*   featsb = (u16*)(ws + off);   off += (size_t)N_NODES*KOP*2;
    u16*   geob   = (u16*)(ws + off);   off += (size_t)N_NODES*HD*2;
    u16*   Wb     = (u16*)(ws + off);   off += (size_t)2*128*KPAD*2;
    u16*   Wop    = (u16*)(ws + off);   off += (size_t)128*KOP*2;
    u16*   Wgeo   = (u16*)(ws + off);   off += (size_t)128*128*2;
    u16*   Wskip  = (u16*)(ws + off);   off += (size_t)128*128*2;
    int*   from_p = (int*)(ws + off);   off += (size_t)N_EDGES*4;
    int*   to_p   = (int*)(ws + off);   off += (size_t)N_EDGES*4;
    uint2* efb_p  = (uint2*)(ws + off); off += (size_t)N_EDGES*8;
    int*   offs   = (int*)(ws + off);   off += (size_t)N_NODES*4;
    char*  zero0  = ws + off;
    u16*   cf_bb  = (u16*)(ws + off);         off += (size_t)N_NODES*HD*2;
    float* cf_b32 = (float*)(ws + off);       off += (size_t)N_NODES*HD*4;
    unsigned* ipf0_m = (unsigned*)(ws + off); off += 128*4;
    float*    ipf1   = (float*)(ws + off);    off += 128*4;
    float*    ipf2   = (float*)(ws + off);    off += 128*4;
    unsigned* pg_m   = (unsigned*)(ws + off); off += 128*4;
    unsigned* sg_m   = (unsigned*)(ws + off); off += 128*4;
    int*      count  = (int*)(ws + off);      off += (size_t)N_NODES*4;
    int*      cursor = (int*)(ws + off);      off += (size_t)N_NODES*4;
    size_t zero_bytes = (size_t)(ws + off - zero0);

    hipMemsetAsync(zero0, 0, zero_bytes, stream);

    prep<<<PREP_GRID, 256, 0, stream>>>(
        edge_w, Wb, op_w, Wop, geo_w, Wgeo, skip_w, Wskip,
        child_feats, featsb, child_geo, geob, eidx, count);

    scan_offsets<<<1, 1024, 0, stream>>>(count, offs);

    // fill_perm + node GEMMs in one launch
    mid<<<1721, 256, 0, stream>>>(
        eidx, etoh, offs, cursor, from_p, to_p, efb_p,
        featsb, geob, child_exists, Wop, op_b, Wgeo, geo_b, Wskip, skip_b,
        cf_a, ipf0_m, pg_m, sg_m);

    // iter 1: MFMA messages + fused in-LDS segment max
    edge_mfma<1><<<N_EDGES/256, 512, 0, stream>>>(
        cf_a, from_p, to_p, efb_p, Wb, edge_b,
        offs, count, cf_bb, cf_b32, (int*)ipf1);

    fixup<<<N_NODES/2, 256, 0, stream>>>(offs, count, cf_b32, cf_bb);

    // iter 2: only column max needed
    edge_mfma<0><<<N_EDGES/256, 512, 0, stream>>>(
        cf_bb, from_p, to_p, efb_p, Wb + 128*KPAD, edge_b + 128,
        offs, count, nullptr, nullptr, (int*)ipf2);

    heads<<<2, 128, 0, stream>>>(ipf0_m, ipf1, ipf2, sec_w, sec_b,
                                 pg_m, sg_m, sgeo_w, sgeo_b, gn_w, gn_b, out);
}